// Round 1
// baseline (290.736 us; speedup 1.0000x reference)
//
#include <hip/hip_runtime.h>

// OU Euler-Maruyama: x_{i+1} = a*x_i + b_i,  a = 1 - gamma*dt (per-chain const),
// b_i = gamma*mu*dt + sigma*sqrt(dt)*eps_i.
// Parallelized via affine-map composition: per-lane 8-step local compose,
// 64-lane wave scan (shfl), sequential carry across tiles within one wave.
// One wave per (n,m) chain: 2048 waves total (grid-limited 2 waves/SIMD).
//
// This version: PF=8-deep software-pipelined prefetch ring (16 KB reads in
// flight per wave vs 2 KB before). The kernel is latency-bound at 2 waves/SIMD
// with a 1-deep pipeline (~55% of achievable HBM BW); Little's law wants
// ~8 KB/wave in flight to sustain 6.5 TB/s at congested-HBM latency.
// Ring slots are statically indexed (outer x5 / unrolled inner x8) so the
// buffers stay in VGPRs, not scratch.

#define T_STEPS 20000
#define M_PATHS 64
#define CHUNK   8            // elements per lane per tile
#define TILE    (64 * CHUNK) // 512
#define NTILES  ((T_STEPS + TILE - 1) / TILE) // 40 (last tile partial: 32 elems)
#define PF      8            // prefetch ring depth (tiles); NTILES % PF == 0
#define DT      0.01f
#define SQRT_DT 0.1f

__global__ __launch_bounds__(256) void ou_scan_kernel(
    const float* __restrict__ theta,
    const float* __restrict__ noise,
    float* __restrict__ out)
{
    const int wave  = threadIdx.x >> 6;
    const int lane  = threadIdx.x & 63;
    const int chain = blockIdx.x * 4 + wave;      // 0 .. 2047
    const int n     = chain / M_PATHS;            // theta row

    const float gamma = theta[n * 4 + 0];
    const float mu    = theta[n * 4 + 1];
    const float sigma = theta[n * 4 + 2];
    float carry       = theta[n * 4 + 3];         // x_0

    const float a    = 1.0f - gamma * DT;
    const float gmdt = gamma * mu * DT;
    const float ssd  = sigma * SQRT_DT;
    const float a2 = a * a;
    const float a4 = a2 * a2;
    const float a8 = a4 * a4;

    const float* __restrict__ np_ = noise + (size_t)chain * T_STEPS;
    float* __restrict__       op_ = out   + (size_t)chain * T_STEPS;

    float4 buf0[PF], buf1[PF];

    // ---- prologue: fill the ring. Tiles 0..PF-1 are all full tiles
    // (PF*TILE = 4096 <= T_STEPS), so no guards needed. 16 loads in flight.
    #pragma unroll
    for (int k = 0; k < PF; ++k) {
        const int e0 = k * TILE + lane * CHUNK;
        buf0[k] = *(const float4*)(np_ + e0);
        buf1[k] = *(const float4*)(np_ + e0 + 4);
    }

    // Per-tile compute: consumes c0/c1, updates carry, stores if cact.
    auto tile_body = [&](const int tb, const float4 c0, const float4 c1,
                         const bool cact) {
        // b_j = gmdt + ssd * eps_j
        const float b0 = fmaf(ssd, c0.x, gmdt);
        const float b1 = fmaf(ssd, c0.y, gmdt);
        const float b2 = fmaf(ssd, c0.z, gmdt);
        const float b3 = fmaf(ssd, c0.w, gmdt);
        const float b4 = fmaf(ssd, c1.x, gmdt);
        const float b5 = fmaf(ssd, c1.y, gmdt);
        const float b6 = fmaf(ssd, c1.z, gmdt);
        const float b7 = fmaf(ssd, c1.w, gmdt);

        // local 8-step affine compose: x_out = a^8 * x_in + p
        float p = b0;
        p = fmaf(p, a, b1);
        p = fmaf(p, a, b2);
        p = fmaf(p, a, b3);
        p = fmaf(p, a, b4);
        p = fmaf(p, a, b5);
        p = fmaf(p, a, b6);
        p = fmaf(p, a, b7);

        float A = cact ? a8 : 1.0f;  // inactive lanes: identity map
        float B = cact ? p  : 0.0f;

        // inclusive wave scan of affine maps (lane order = time order)
        #pragma unroll
        for (int d = 1; d < 64; d <<= 1) {
            const float pA = __shfl_up(A, d);
            const float pB = __shfl_up(B, d);
            if (lane >= d) {
                B = fmaf(A, pB, B);   // cur ∘ prev : A*(pA x + pB) + B
                A = A * pA;
            }
        }

        // exclusive prefix for this lane
        float Aex = __shfl_up(A, 1);
        float Bex = __shfl_up(B, 1);
        if (lane == 0) { Aex = 1.0f; Bex = 0.0f; }
        float x = fmaf(Aex, carry, Bex);   // state entering this lane's chunk

        // carry across tiles: lane 63's inclusive map applied to carry
        const float A63 = __shfl(A, 63);
        const float B63 = __shfl(B, 63);
        carry = fmaf(A63, carry, B63);

        if (cact) {
            const int base = tb * TILE + lane * CHUNK;
            float4 o0, o1;
            x = fmaf(a, x, b0); o0.x = x;
            x = fmaf(a, x, b1); o0.y = x;
            x = fmaf(a, x, b2); o0.z = x;
            x = fmaf(a, x, b3); o0.w = x;
            x = fmaf(a, x, b4); o1.x = x;
            x = fmaf(a, x, b5); o1.y = x;
            x = fmaf(a, x, b6); o1.z = x;
            x = fmaf(a, x, b7); o1.w = x;
            *(float4*)(op_ + base)     = o0;
            *(float4*)(op_ + base + 4) = o1;
        }
    };

    // ---- main loop: tiles 0..NTILES-PF-1 (all full tiles -> no cact branch),
    // each iteration re-arms its ring slot with tile tb+PF.
    for (int t0 = 0; t0 + PF < NTILES; t0 += PF) {   // t0 = 0,8,16,24
        #pragma unroll
        for (int k = 0; k < PF; ++k) {
            const int tb = t0 + k;
            const float4 c0 = buf0[k];
            const float4 c1 = buf1[k];
            // prefetch tile tb+PF into slot k (per-lane guard only matters
            // for the final partial tile 39; stale regs on inactive lanes are
            // harmless: that tile's lanes are identity maps and don't store)
            const int ne0 = (tb + PF) * TILE + lane * CHUNK;
            if (ne0 + CHUNK <= T_STEPS) {
                buf0[k] = *(const float4*)(np_ + ne0);
                buf1[k] = *(const float4*)(np_ + ne0 + 4);
            }
            tile_body(tb, c0, c1, true);
        }
    }

    // ---- epilogue: last PF tiles (tile NTILES-1 partial), no prefetch ----
    #pragma unroll
    for (int k = 0; k < PF; ++k) {
        const int tb = (NTILES - PF) + k;
        const int base = tb * TILE + lane * CHUNK;
        tile_body(tb, buf0[k], buf1[k], base + CHUNK <= T_STEPS);
    }
}

extern "C" void kernel_launch(void* const* d_in, const int* in_sizes, int n_in,
                              void* d_out, int out_size, void* d_ws, size_t ws_size,
                              hipStream_t stream) {
    const float* theta = (const float*)d_in[0];
    const float* noise = (const float*)d_in[1];
    float* out = (float*)d_out;

    const int chains = in_sizes[1] / T_STEPS;   // 2048
    const int blocks = chains / 4;              // 4 waves (chains) per 256-thr block
    ou_scan_kernel<<<blocks, 256, 0, stream>>>(theta, noise, out);
}

// Round 2
// 288.763 us; speedup vs baseline: 1.0068x; 1.0068x over previous
//
#include <hip/hip_runtime.h>

// OU Euler-Maruyama: x_{i+1} = a*x_i + b_i,  a = 1 - gamma*dt (per-chain const),
// b_i = gamma*mu*dt + sigma*sqrt(dt)*eps_i.
//
// Block-level affine scan: ONE 256-thread block (4 waves) per chain.
//  - per lane: 8-step local affine compose (registers)
//  - per wave: 64-lane shfl scan of affine maps
//  - per block: lane-63 wave maps -> LDS (double-buffered), 1 barrier,
//    each wave composes its exclusive wave-prefix + full-block carry map
//  - sequential carry across 10 block-tiles of 2048 steps
//
// Rationale (round-1 post-mortem): the 1-wave-per-chain version was stuck at
// 2 waves/SIMD (Occupancy 19%), 6200 cy/tile of stall; deeper per-wave
// prefetch (PF=8) changed nothing -> latency hiding must come from TLP.
// This version runs 8192 waves = 32 waves/CU (max occupancy) and cuts the
// serial tile chain per wave 40 -> 10.

#define T_STEPS 20000
#define M_PATHS 64
#define CHUNK   8                       // elements per lane per tile
#define NWAVES  4
#define BLOCK   (NWAVES * 64)           // 256
#define BTILE   (BLOCK * CHUNK)         // 2048 steps per block-tile
#define NBT     ((T_STEPS + BTILE - 1) / BTILE)  // 10 (last tile: 1568 elems)
#define DT      0.01f
#define SQRT_DT 0.1f

__global__ __launch_bounds__(BLOCK, 8) void ou_scan_kernel(
    const float* __restrict__ theta,
    const float* __restrict__ noise,
    float* __restrict__ out)
{
    __shared__ float sA[2][NWAVES], sB[2][NWAVES];

    const int tid   = threadIdx.x;
    const int wave  = tid >> 6;
    const int lane  = tid & 63;
    const int chain = blockIdx.x;            // 0 .. 2047
    const int n     = chain >> 6;            // chain / M_PATHS -> theta row

    const float gamma = theta[n * 4 + 0];
    const float mu    = theta[n * 4 + 1];
    const float sigma = theta[n * 4 + 2];
    float carry       = theta[n * 4 + 3];    // x_0 (uniform across block)

    const float a    = 1.0f - gamma * DT;
    const float gmdt = gamma * mu * DT;
    const float ssd  = sigma * SQRT_DT;
    const float a2 = a * a;
    const float a4 = a2 * a2;
    const float a8 = a4 * a4;

    const float* __restrict__ np_ = noise + (size_t)chain * T_STEPS;
    float* __restrict__       op_ = out   + (size_t)chain * T_STEPS;

    // ---- prefetch tile 0 (always a full tile: BTILE <= T_STEPS) ----
    float4 c0, c1;
    {
        const int e0 = tid * CHUNK;
        c0 = *(const float4*)(np_ + e0);
        c1 = *(const float4*)(np_ + e0 + 4);
    }

    for (int tb = 0; tb < NBT; ++tb) {
        // ---- prefetch next tile (in flight across this tile's compute) ----
        float4 n0 = make_float4(0.f, 0.f, 0.f, 0.f);
        float4 n1 = make_float4(0.f, 0.f, 0.f, 0.f);
        const int ne0 = (tb + 1) * BTILE + tid * CHUNK;
        if (ne0 + CHUNK <= T_STEPS) {
            n0 = *(const float4*)(np_ + ne0);
            n1 = *(const float4*)(np_ + ne0 + 4);
        }

        const int  base = tb * BTILE + tid * CHUNK;
        const bool act  = (base + CHUNK <= T_STEPS);

        // b_j = gmdt + ssd * eps_j
        const float b0 = fmaf(ssd, c0.x, gmdt);
        const float b1 = fmaf(ssd, c0.y, gmdt);
        const float b2 = fmaf(ssd, c0.z, gmdt);
        const float b3 = fmaf(ssd, c0.w, gmdt);
        const float b4 = fmaf(ssd, c1.x, gmdt);
        const float b5 = fmaf(ssd, c1.y, gmdt);
        const float b6 = fmaf(ssd, c1.z, gmdt);
        const float b7 = fmaf(ssd, c1.w, gmdt);

        // local 8-step affine compose: x_out = a^8 * x_in + p
        float p = b0;
        p = fmaf(p, a, b1);
        p = fmaf(p, a, b2);
        p = fmaf(p, a, b3);
        p = fmaf(p, a, b4);
        p = fmaf(p, a, b5);
        p = fmaf(p, a, b6);
        p = fmaf(p, a, b7);

        float A = act ? a8 : 1.0f;   // inactive (tail) lanes: identity map
        float B = act ? p  : 0.0f;

        // inclusive wave scan of affine maps (lane order = time order)
        #pragma unroll
        for (int d = 1; d < 64; d <<= 1) {
            const float pA = __shfl_up(A, d);
            const float pB = __shfl_up(B, d);
            if (lane >= d) {
                B = fmaf(A, pB, B);   // cur ∘ prev : A*(pA x + pB) + B
                A = A * pA;
            }
        }

        // publish wave map; double-buffered so ONE barrier per tile suffices
        if (lane == 63) { sA[tb & 1][wave] = A; sB[tb & 1][wave] = B; }
        __syncthreads();

        // exclusive wave-prefix (PA,PB) and full-block map (FA,FB)
        float PA = 1.f, PB = 0.f, FA = 1.f, FB = 0.f;
        #pragma unroll
        for (int w = 0; w < NWAVES; ++w) {
            const float aw = sA[tb & 1][w];   // broadcast reads, conflict-free
            const float bw = sB[tb & 1][w];
            if (w < wave) { PB = fmaf(aw, PB, bw); PA *= aw; }
            FB = fmaf(aw, FB, bw); FA *= aw;
        }

        const float xw = fmaf(PA, carry, PB);   // state entering this wave

        // exclusive lane prefix within the wave
        float Aex = __shfl_up(A, 1);
        float Bex = __shfl_up(B, 1);
        if (lane == 0) { Aex = 1.f; Bex = 0.f; }
        float x = fmaf(Aex, xw, Bex);           // state entering this lane

        carry = fmaf(FA, carry, FB);            // carry across block-tiles

        if (act) {
            float4 o0, o1;
            x = fmaf(a, x, b0); o0.x = x;
            x = fmaf(a, x, b1); o0.y = x;
            x = fmaf(a, x, b2); o0.z = x;
            x = fmaf(a, x, b3); o0.w = x;
            x = fmaf(a, x, b4); o1.x = x;
            x = fmaf(a, x, b5); o1.y = x;
            x = fmaf(a, x, b6); o1.z = x;
            x = fmaf(a, x, b7); o1.w = x;
            *(float4*)(op_ + base)     = o0;
            *(float4*)(op_ + base + 4) = o1;
        }

        c0 = n0;
        c1 = n1;
    }
}

extern "C" void kernel_launch(void* const* d_in, const int* in_sizes, int n_in,
                              void* d_out, int out_size, void* d_ws, size_t ws_size,
                              hipStream_t stream) {
    const float* theta = (const float*)d_in[0];
    const float* noise = (const float*)d_in[1];
    float* out = (float*)d_out;

    const int chains = in_sizes[1] / T_STEPS;   // 2048
    ou_scan_kernel<<<chains, BLOCK, 0, stream>>>(theta, noise, out);
}